// Round 12
// baseline (396.551 us; speedup 1.0000x reference)
//
#include <hip/hip_runtime.h>
#include <cstdint>
#include <cstddef>

// Problem constants: B=8, T=8, C=512, R=128, H=W=56, HW=3136, BT=64
#define HW   3136
#define WROW 56
#define CIN  512
#define RMID 128
#define HWQ  196   // HW/16

typedef unsigned int  u32;
typedef unsigned short u16;
typedef __attribute__((ext_vector_type(8))) short s16x8;   // 8 bf16 = 4 VGPR
typedef __attribute__((ext_vector_type(4))) float f32x4;   // MFMA acc / nt IO

__device__ __forceinline__ u16 f2bf(float f) {             // f32->bf16 RNE
    u32 u = __float_as_uint(f);
    u32 r = u + 0x7fffu + ((u >> 16) & 1u);
    return (u16)(r >> 16);
}
__device__ __forceinline__ float bf2f(u32 bits16) {
    return __uint_as_float(bits16 << 16);
}
__device__ __forceinline__ u32 pk2(float a, float b) {
    return (u32)f2bf(a) | ((u32)f2bf(b) << 16);
}

// ---------------------------------------------------------------------------
// Prep: pack W_down (128x512) and W_up (512x128) into MFMA fragment order.
// Frag k-mapping (shared by ALL MFMA users in this file): k = lg*8 + j,
// lg = lane>>4. Fragment for (k-step s, tile): lane l holds
// W[tile*16 + (l&15)][s*32 + lg*8 + j], stored at ((g*64)+l)*8+j so a frag
// load is one contiguous-1KB-per-wave b128 read. The same bytes serve as an
// A-frag (rows = l&15) or a B-frag (cols = l&15) depending on operand slot.
// ---------------------------------------------------------------------------
__global__ __launch_bounds__(256) void kprep(
    const float* __restrict__ Wd, const float* __restrict__ Wu,
    u16* __restrict__ wdf, u16* __restrict__ wuf)
{
    const int t = blockIdx.x * 256 + threadIdx.x;   // 0..16383
    const int l = t & 63, g = t >> 6;               // g 0..255
    const int lo = l & 15, hi = l >> 4;
    const float* src;
    u16* dst;
    if (g < 128) {                                  // W_down: s(16) x m(8)
        const int s = g >> 3, m = g & 7;
        src = Wd + (size_t)(m * 16 + lo) * CIN + s * 32 + hi * 8;
        dst = wdf + (size_t)t * 8;                  // (g*64+l)*8
    } else {                                        // W_up: mt(32) x s(4)
        const int g2 = g - 128;
        const int mt = g2 >> 2, s = g2 & 3;
        src = Wu + (size_t)(mt * 16 + lo) * RMID + s * 32 + hi * 8;
        dst = wuf + (size_t)(t - 8192) * 8;
    }
    float4 a = *(const float4*)src;
    float4 b = *(const float4*)(src + 4);
    uint4 o;
    o.x = pk2(a.x, a.y); o.y = pk2(a.z, a.w);
    o.z = pk2(b.x, b.y); o.w = pk2(b.z, b.w);
    *(uint4*)dst = o;
}

// ---------------------------------------------------------------------------
// k1: conv_down (M=128, K=512, N=px) via bf16 MFMA + LayerNorm stats.
// Round 12: 2-DEEP load prefetch. Two register sets vA/vB; loads for step
// s+2 are issued in iteration s, so the vmcnt wait in pack(s+1) has a FULL
// iteration (16 MFMA + barrier + next issue) of cover instead of ~16 MFMA.
// Loop unrolled x2 with named vA/vB (static register indexing). One barrier
// per step, 2-buffer LDS unchanged. Hazards: pack(->buf[(s+1)&1]) in iter s
// is after the barrier that ended that buffer's last read (iter s-1).
// ---------------------------------------------------------------------------
__global__ __launch_bounds__(256) void k1_down_ln(
    const float* __restrict__ x, const u16* __restrict__ wdf,
    const float* __restrict__ bd, u16* __restrict__ hd,
    float* __restrict__ st)
{
    __shared__ u16 xl[2][128 * 40];    // 20.4 KB double-buffered

    const int tid  = threadIdx.x;
    const int lane = tid & 63, w = tid >> 6;
    // bijective XCD-chunked remap: grid 1600 = 8 xcd * 8 bt * 25 chunks
    const int h = blockIdx.x;
    const int slot = h >> 3;                    // 0..199
    const int bt = (h & 7) * 8 + slot / 25;
    const int px0 = (slot % 25) * 128;
    const int b = bt >> 3, t = bt & 7;

    // staging role: wave w = c-oct w; lane = px-pair (2 px per thread)
    const int pxp2 = px0 + 2 * lane;
    const int pxa = (pxp2 > HW - 2) ? (HW - 2) : pxp2;   // clamp tail (dup reads)
    const float* xb = x + (size_t)bt * CIN * HW + pxa;

    // compute role
    const int p16 = lane & 15, lg = lane >> 4;

    float2 vA[8], vB[8];
    auto loads = [&](float2 (&v)[8], int s) {
        const float* xs = xb + (size_t)(s * 32 + w * 8) * HW;
#pragma unroll
        for (int j = 0; j < 8; ++j)
            v[j] = *(const float2*)(xs + (size_t)j * HW);
    };
    auto packw = [&](float2 (&v)[8], int buf) {
        uint4 pkA, pkB;
        pkA.x = pk2(v[0].x, v[1].x); pkA.y = pk2(v[2].x, v[3].x);
        pkA.z = pk2(v[4].x, v[5].x); pkA.w = pk2(v[6].x, v[7].x);
        pkB.x = pk2(v[0].y, v[1].y); pkB.y = pk2(v[2].y, v[3].y);
        pkB.z = pk2(v[4].y, v[5].y); pkB.w = pk2(v[6].y, v[7].y);
        *(uint4*)&xl[buf][(size_t)(2 * lane)     * 40 + w * 8] = pkA;
        *(uint4*)&xl[buf][(size_t)(2 * lane + 1) * 40 + w * 8] = pkB;
    };

    f32x4 acc[8][2];
    const f32x4 zz = {0.f, 0.f, 0.f, 0.f};
#pragma unroll
    for (int m = 0; m < 8; ++m) { acc[m][0] = zz; acc[m][1] = zz; }

    auto mfma_step = [&](int s, const u16* xbuf) {
        s16x8 bf0 = *(const s16x8*)&xbuf[(w * 32 +      p16) * 40 + lg * 8];
        s16x8 bf1 = *(const s16x8*)&xbuf[(w * 32 + 16 + p16) * 40 + lg * 8];
#pragma unroll
        for (int m = 0; m < 8; ++m) {
            s16x8 af = *(const s16x8*)(wdf + ((size_t)((s * 8 + m) * 64 + lane)) * 8);
            acc[m][0] = __builtin_amdgcn_mfma_f32_16x16x32_bf16(af, bf0, acc[m][0], 0, 0, 0);
            acc[m][1] = __builtin_amdgcn_mfma_f32_16x16x32_bf16(af, bf1, acc[m][1], 0, 0, 0);
        }
    };

    loads(vA, 0);
    loads(vB, 1);
    packw(vA, 0);
    __syncthreads();

#pragma unroll 1
    for (int s2 = 0; s2 < 16; s2 += 2) {
        // even step s2: compute buf0; vB holds s2+1 (issued 1 iter ago)
        if (s2 + 2 < 16) loads(vA, s2 + 2);
        mfma_step(s2, xl[0]);
        packw(vB, 1);
        __syncthreads();
        // odd step s2+1: compute buf1; vA holds s2+2
        if (s2 + 3 < 16) loads(vB, s2 + 3);
        mfma_step(s2 + 1, xl[1]);
        if (s2 + 2 < 16) packw(vA, 0);
        __syncthreads();
    }

    // epilogue: bias, hd store (bf16), LN stats
#pragma unroll
    for (int n = 0; n < 2; ++n) {
        const int hwpx = px0 + w * 32 + n * 16 + p16;
        const bool ok = hwpx < HW;
        float sum = 0.f, sq = 0.f;
        const size_t hbase = ((size_t)(b * HW + (ok ? hwpx : 0)) * 8 + t) * 128 + lg * 4;
#pragma unroll
        for (int m = 0; m < 8; ++m) {
            float4 bv = *(const float4*)(bd + m * 16 + lg * 4);
            float v0 = acc[m][n].x + bv.x;
            float v1 = acc[m][n].y + bv.y;
            float v2 = acc[m][n].z + bv.z;
            float v3 = acc[m][n].w + bv.w;
            sum += v0 + v1 + v2 + v3;
            sq  += v0*v0 + v1*v1 + v2*v2 + v3*v3;
            if (ok) {
                ushort4 o;
                o.x = f2bf(v0); o.y = f2bf(v1); o.z = f2bf(v2); o.w = f2bf(v3);
                *(ushort4*)(hd + hbase + m * 16) = o;
            }
        }
        // reduce the 4 lane-groups holding this pixel's 128 channels
        sum += __shfl_xor(sum, 16); sum += __shfl_xor(sum, 32);
        sq  += __shfl_xor(sq, 16);  sq  += __shfl_xor(sq, 32);
        if (ok && lg == 0) {
            float mu  = sum * (1.f / 128.f);
            float var = sq  * (1.f / 128.f) - mu * mu;
            float2 s2v = make_float2(mu, rsqrtf(var + 1e-5f));
            *(float2*)(st + ((size_t)(b * HW + hwpx) * 8 + t) * 2) = s2v;
        }
    }
}

// ---------------------------------------------------------------------------
// k2a: motion shift + 8x8 self-attention + residual. One wave per pixel,
// 4 px/block. XCD-chunked mapping: XCD x owns batch b = x, so the (h+1)-row
// hd re-read hits the same XCD's L2 (unchanged from R9).
// ---------------------------------------------------------------------------
__global__ __launch_bounds__(256) void k2a_attn(
    const u16* __restrict__ hd, const float* __restrict__ st,
    u16* __restrict__ h2f)
{
    __shared__ float ql[4][8 * 132];
    __shared__ float pl[4][8][9];

    const int tid = threadIdx.x, wid = tid >> 6, lane = tid & 63;
    const int h = blockIdx.x;                        // 0..6271
    const int P = ((h & 7) * 784 + (h >> 3)) * 4 + wid;
    const int b = P / HW;
    const int hw = P - b * HW;
    const int hrow = hw / WROW;
    const bool hasnext = hrow < (WROW - 1);

    const u16* cur = hd + (size_t)P * 1024;
    const int tq = lane >> 3, cbase = (lane & 7) * 16;   // this lane: t=tq, c=cbase..+15

    uint4 c0 = *(const uint4*)(cur + tq * 128 + cbase);
    uint4 c1 = *(const uint4*)(cur + tq * 128 + cbase + 8);
    float2 ms = *(const float2*)(st + ((size_t)P * 8 + tq) * 2);

    float hv[16];
    hv[0]=bf2f(c0.x&0xffff); hv[1]=bf2f(c0.x>>16); hv[2]=bf2f(c0.y&0xffff); hv[3]=bf2f(c0.y>>16);
    hv[4]=bf2f(c0.z&0xffff); hv[5]=bf2f(c0.z>>16); hv[6]=bf2f(c0.w&0xffff); hv[7]=bf2f(c0.w>>16);
    hv[8]=bf2f(c1.x&0xffff); hv[9]=bf2f(c1.x>>16); hv[10]=bf2f(c1.y&0xffff); hv[11]=bf2f(c1.y>>16);
    hv[12]=bf2f(c1.z&0xffff); hv[13]=bf2f(c1.z>>16); hv[14]=bf2f(c1.w&0xffff); hv[15]=bf2f(c1.w>>16);

    float qv[16];
    if (hasnext) {
        const u16* nx = cur + (size_t)WROW * 1024;
        uint4 n0 = *(const uint4*)(nx + tq * 128 + cbase);
        uint4 n1 = *(const uint4*)(nx + tq * 128 + cbase + 8);
        float2 mn = *(const float2*)(st + ((size_t)(P + WROW) * 8 + tq) * 2);
        float nv[16];
        nv[0]=bf2f(n0.x&0xffff); nv[1]=bf2f(n0.x>>16); nv[2]=bf2f(n0.y&0xffff); nv[3]=bf2f(n0.y>>16);
        nv[4]=bf2f(n0.z&0xffff); nv[5]=bf2f(n0.z>>16); nv[6]=bf2f(n0.w&0xffff); nv[7]=bf2f(n0.w>>16);
        nv[8]=bf2f(n1.x&0xffff); nv[9]=bf2f(n1.x>>16); nv[10]=bf2f(n1.y&0xffff); nv[11]=bf2f(n1.y>>16);
        nv[12]=bf2f(n1.z&0xffff); nv[13]=bf2f(n1.z>>16); nv[14]=bf2f(n1.w&0xffff); nv[15]=bf2f(n1.w>>16);
#pragma unroll
        for (int i = 0; i < 16; ++i)
            qv[i] = (nv[i] - mn.x) * mn.y - (hv[i] - ms.x) * ms.y;
    } else {
#pragma unroll
        for (int i = 0; i < 16; ++i)
            qv[i] = -(hv[i] - ms.x) * ms.y;
    }

    float* qrow = &ql[wid][tq * 132 + cbase];
#pragma unroll
    for (int i = 0; i < 4; ++i)
        *(float4*)(qrow + i * 4) = make_float4(qv[4*i], qv[4*i+1], qv[4*i+2], qv[4*i+3]);
    __syncthreads();

    // S[t][s] = q[t].q[s]/sqrt(128); lane = t*8+s
    const int tt = lane >> 3, ss = lane & 7;
    const float* qt = &ql[wid][tt * 132];
    const float* qs = &ql[wid][ss * 132];
    float dot = 0.f;
#pragma unroll 8
    for (int c4 = 0; c4 < 32; ++c4) {
        float4 a4 = *(const float4*)(qt + c4 * 4);
        float4 g4 = *(const float4*)(qs + c4 * 4);
        dot += a4.x*g4.x + a4.y*g4.y + a4.z*g4.z + a4.w*g4.w;
    }
    dot *= 0.08838834764831845f;   // 1/sqrt(128)
    float mx = dot;
    mx = fmaxf(mx, __shfl_xor(mx, 1));
    mx = fmaxf(mx, __shfl_xor(mx, 2));
    mx = fmaxf(mx, __shfl_xor(mx, 4));
    float e = __expf(dot - mx);
    float sm = e;
    sm += __shfl_xor(sm, 1); sm += __shfl_xor(sm, 2); sm += __shfl_xor(sm, 4);
    pl[wid][tt][ss] = e / sm;
    __syncthreads();

    // attn = P @ q + residual(hd)
    float at[16];
#pragma unroll
    for (int i = 0; i < 16; ++i) at[i] = hv[i];
#pragma unroll
    for (int s = 0; s < 8; ++s) {
        float p = pl[wid][tq][s];
        const float* qsr = &ql[wid][s * 132 + cbase];
#pragma unroll
        for (int i4 = 0; i4 < 4; ++i4) {
            float4 q4 = *(const float4*)(qsr + i4 * 4);
            at[4*i4+0] += p * q4.x; at[4*i4+1] += p * q4.y;
            at[4*i4+2] += p * q4.z; at[4*i4+3] += p * q4.w;
        }
    }

    // store in k2b fragment layout
    const int hwq = hw >> 4, pp = hw & 15;
    const size_t base = ((((size_t)(b * 8 + tq) * HWQ + hwq) * 16 + (cbase >> 3)) * 16 + pp) * 8;
    uint4 o0, o1;
    o0.x = pk2(at[0], at[1]);  o0.y = pk2(at[2], at[3]);
    o0.z = pk2(at[4], at[5]);  o0.w = pk2(at[6], at[7]);
    o1.x = pk2(at[8], at[9]);  o1.y = pk2(at[10], at[11]);
    o1.z = pk2(at[12], at[13]); o1.w = pk2(at[14], at[15]);
    *(uint4*)(h2f + base) = o0;
    *(uint4*)(h2f + base + 128) = o1;   // rq+1 (stride 16px*8e)
}

// ---------------------------------------------------------------------------
// k2b: conv_up (M=px, N=16 o, K=128) + sigmoid gate + residual.
// Nontemporal out stores + x loads (R11 winner, byte-identical). 4
// independent waves/block, no barriers, private LDS slabs, XCD-chunked.
// ---------------------------------------------------------------------------
__global__ __launch_bounds__(256, 8) void k2b_up_out(
    const u16* __restrict__ h2f, const u16* __restrict__ wuf,
    const float* __restrict__ bu, const float* __restrict__ x,
    float* __restrict__ out)
{
    __shared__ float sl[4][16 * 68];       // per-wave private slabs, 17.4 KB

    const int tid = threadIdx.x, lane = tid & 63, w = tid >> 6;
    const int h = blockIdx.x;              // 0..2047
    const int slot = h >> 3;               // 0..255
    const int bt = (h & 7) * 8 + (slot >> 5);
    const int oc = slot & 31;              // o-chunk: o = oc*16 .. +15
    const int q  = w;                      // wave = px-quarter phase
    const int p16 = lane & 15, lg = lane >> 4;
    float* slw = sl[w];

    // B-frags: W_up rows o = oc*16 + p16, k = s*32 + lg*8 + j (live all kernel)
    s16x8 wf[4];
#pragma unroll
    for (int s = 0; s < 4; ++s)
        wf[s] = *(const s16x8*)(wuf + ((size_t)((oc * 4 + s) * 64 + lane)) * 8);

    // bias for this lane's 4 readback rows (row ol = i*4 + lg)
    float bvr[4];
#pragma unroll
    for (int i = 0; i < 4; ++i) bvr[i] = bu[oc * 16 + i * 4 + lg];

    const u16* bp0 = h2f + (size_t)bt * HWQ * 2048;
    const size_t xrow = (size_t)bt * CIN * HW + (size_t)(oc * 16) * HW;

    const int ng = (q == 0) ? 13 : 12;     // wave 0 of each (bt,oc) takes tail
    for (int it = 0; it < ng; ++it) {
        const int g = (it < 12) ? (it * 4 + q) : 48;   // 64-px group id
        const int px0 = g * 64;

        // 1. prefetch x for this group (nontemporal: zero reuse, don't allocate)
        f32x4 xv[4];
#pragma unroll
        for (int i = 0; i < 4; ++i)
            xv[i] = __builtin_nontemporal_load(
                (const f32x4*)(x + xrow + (size_t)(i * 4 + lg) * HW + px0 + p16 * 4));

        // 2. four 16-px MFMA tiles -> LDS slab [o=p16][px_local]
#pragma unroll
        for (int tt = 0; tt < 4; ++tt) {
            const u16* bp = bp0 + (size_t)(g * 4 + tt) * 2048;
            f32x4 a = {0.f, 0.f, 0.f, 0.f};
#pragma unroll
            for (int s = 0; s < 4; ++s) {
                s16x8 af = *(const s16x8*)(bp + ((size_t)((s * 4 + lg) * 16 + p16)) * 8);
                a = __builtin_amdgcn_mfma_f32_16x16x32_bf16(af, wf[s], a, 0, 0, 0);
            }
            // D: col=p16 -> o_local, row=lg*4+r -> px within tile
            *(f32x4*)&slw[p16 * 68 + tt * 16 + lg * 4] = a;
        }
        // intra-wave LDS dependency: compiler inserts lgkmcnt, no barrier.

        // 3. readback px-major + gate + nontemporal store
#pragma unroll
        for (int i = 0; i < 4; ++i) {
            const int ol = i * 4 + lg;
            f32x4 a4 = *(const f32x4*)&slw[ol * 68 + p16 * 4];
            const size_t off = xrow + (size_t)ol * HW + px0 + p16 * 4;
            f32x4 rr;
            rr.x = xv[i].x * (1.f + 1.f / (1.f + __expf(-(a4.x + bvr[i]))));
            rr.y = xv[i].y * (1.f + 1.f / (1.f + __expf(-(a4.y + bvr[i]))));
            rr.z = xv[i].z * (1.f + 1.f / (1.f + __expf(-(a4.z + bvr[i]))));
            rr.w = xv[i].w * (1.f + 1.f / (1.f + __expf(-(a4.w + bvr[i]))));
            __builtin_nontemporal_store(rr, (f32x4*)(out + off));
        }
    }
}

// ---------------------------------------------------------------------------
extern "C" void kernel_launch(void* const* d_in, const int* in_sizes, int n_in,
                              void* d_out, int out_size, void* d_ws, size_t ws_size,
                              hipStream_t stream)
{
    (void)in_sizes; (void)n_in; (void)out_size; (void)ws_size;
    const float* x  = (const float*)d_in[0];
    const float* Wd = (const float*)d_in[1];
    const float* bd = (const float*)d_in[2];
    const float* Wu = (const float*)d_in[3];
    const float* bu = (const float*)d_in[4];
    float* out = (float*)d_out;

    // workspace (bytes, all 256-aligned):
    //   hd  : 25,690,112 bf16 = 51,380,224   (conv_down out, (b,hw,t,c))
    //   h2f : 25,690,112 bf16 = 51,380,224   (attn out, k2b frag layout)
    //   st  :    401,408 f32  =  1,605,632   (LN mu/rstd per (pixel,t))
    //   wdf :     65,536 bf16 =    131,072   (W_down frag-packed)
    //   wuf :     65,536 bf16 =    131,072   (W_up   frag-packed)
    char* wsp = (char*)d_ws;
    u16*  hd  = (u16*)wsp;                 wsp += 51380224;
    u16*  h2f = (u16*)wsp;                 wsp += 51380224;
    float* st = (float*)wsp;               wsp += 1605632;
    u16*  wdf = (u16*)wsp;                 wsp += 131072;
    u16*  wuf = (u16*)wsp;                 wsp += 131072;

    kprep     <<<dim3(64),   256, 0, stream>>>(Wd, Wu, wdf, wuf);
    k1_down_ln<<<dim3(1600), 256, 0, stream>>>(x, wdf, bd, hd, st);
    k2a_attn  <<<dim3(6272), 256, 0, stream>>>(hd, st, h2f);
    k2b_up_out<<<dim3(2048), 256, 0, stream>>>(h2f, wuf, bu, x, out);
}

// Round 13
// 378.892 us; speedup vs baseline: 1.0466x; 1.0466x over previous
//
#include <hip/hip_runtime.h>
#include <cstdint>
#include <cstddef>

// Problem constants: B=8, T=8, C=512, R=128, H=W=56, HW=3136, BT=64
#define HW   3136
#define WROW 56
#define CIN  512
#define RMID 128
#define HWQ  196   // HW/16

typedef unsigned int  u32;
typedef unsigned short u16;
typedef __attribute__((ext_vector_type(8))) short s16x8;   // 8 bf16 = 4 VGPR
typedef __attribute__((ext_vector_type(4))) float f32x4;   // MFMA acc / nt IO

__device__ __forceinline__ u16 f2bf(float f) {             // f32->bf16 RNE
    u32 u = __float_as_uint(f);
    u32 r = u + 0x7fffu + ((u >> 16) & 1u);
    return (u16)(r >> 16);
}
__device__ __forceinline__ float bf2f(u32 bits16) {
    return __uint_as_float(bits16 << 16);
}
__device__ __forceinline__ u32 pk2(float a, float b) {
    return (u32)f2bf(a) | ((u32)f2bf(b) << 16);
}
// HW packed conversion: dst = {lo: bf16(a), hi: bf16(b)} — single VALU instr,
// RNE (same as pk2 on normal values). No builtin on gfx950 -> inline asm.
__device__ __forceinline__ u32 cvtpk(float a, float b) {
    u32 r;
    asm("v_cvt_pk_bf16_f32 %0, %1, %2" : "=v"(r) : "v"(a), "v"(b));
    return r;
}

// ---------------------------------------------------------------------------
// Prep: pack W_down (128x512) and W_up (512x128) into MFMA fragment order.
// Frag k-mapping (shared by ALL MFMA users in this file): k = lg*8 + j,
// lg = lane>>4. Fragment for (k-step s, tile): lane l holds
// W[tile*16 + (l&15)][s*32 + lg*8 + j], stored at ((g*64)+l)*8+j so a frag
// load is one contiguous-1KB-per-wave b128 read. The same bytes serve as an
// A-frag (rows = l&15) or a B-frag (cols = l&15) depending on operand slot.
// ---------------------------------------------------------------------------
__global__ __launch_bounds__(256) void kprep(
    const float* __restrict__ Wd, const float* __restrict__ Wu,
    u16* __restrict__ wdf, u16* __restrict__ wuf)
{
    const int t = blockIdx.x * 256 + threadIdx.x;   // 0..16383
    const int l = t & 63, g = t >> 6;               // g 0..255
    const int lo = l & 15, hi = l >> 4;
    const float* src;
    u16* dst;
    if (g < 128) {                                  // W_down: s(16) x m(8)
        const int s = g >> 3, m = g & 7;
        src = Wd + (size_t)(m * 16 + lo) * CIN + s * 32 + hi * 8;
        dst = wdf + (size_t)t * 8;                  // (g*64+l)*8
    } else {                                        // W_up: mt(32) x s(4)
        const int g2 = g - 128;
        const int mt = g2 >> 2, s = g2 & 3;
        src = Wu + (size_t)(mt * 16 + lo) * RMID + s * 32 + hi * 8;
        dst = wuf + (size_t)(t - 8192) * 8;
    }
    float4 a = *(const float4*)src;
    float4 b = *(const float4*)(src + 4);
    uint4 o;
    o.x = pk2(a.x, a.y); o.y = pk2(a.z, a.w);
    o.z = pk2(b.x, b.y); o.w = pk2(b.z, b.w);
    *(uint4*)dst = o;
}

// ---------------------------------------------------------------------------
// k1: conv_down (M=128, K=512, N=px) via bf16 MFMA + LayerNorm stats.
// Round 13: R11 structure (1-deep prefetch, 2-buffer LDS, one barrier/step)
// + v_cvt_pk_bf16_f32 for ALL f32->bf16 packing (8 instrs/step instead of
// ~60 VALU bit-twiddle ops — the compiler can't pattern-match manual RNE
// into cvt_pk). Epilogue hd-store conversion also cvt_pk.
// ---------------------------------------------------------------------------
__global__ __launch_bounds__(256) void k1_down_ln(
    const float* __restrict__ x, const u16* __restrict__ wdf,
    const float* __restrict__ bd, u16* __restrict__ hd,
    float* __restrict__ st)
{
    __shared__ u16 xl[2][128 * 40];    // 20.4 KB double-buffered

    const int tid  = threadIdx.x;
    const int lane = tid & 63, w = tid >> 6;
    // bijective XCD-chunked remap: grid 1600 = 8 xcd * 8 bt * 25 chunks
    const int h = blockIdx.x;
    const int slot = h >> 3;                    // 0..199
    const int bt = (h & 7) * 8 + slot / 25;
    const int px0 = (slot % 25) * 128;
    const int b = bt >> 3, t = bt & 7;

    // staging role: wave w = c-oct w; lane = px-pair (2 px per thread)
    const int pxp2 = px0 + 2 * lane;
    const int pxa = (pxp2 > HW - 2) ? (HW - 2) : pxp2;   // clamp tail (dup reads)
    const float* xb = x + (size_t)bt * CIN * HW + pxa;

    // compute role
    const int p16 = lane & 15, lg = lane >> 4;

    float2 v[8];
    auto loads = [&](int s) {
        const float* xs = xb + (size_t)(s * 32 + w * 8) * HW;
#pragma unroll
        for (int j = 0; j < 8; ++j)
            v[j] = *(const float2*)(xs + (size_t)j * HW);
    };
    auto packw = [&](int buf) {
        uint4 pkA, pkB;
        pkA.x = cvtpk(v[0].x, v[1].x); pkA.y = cvtpk(v[2].x, v[3].x);
        pkA.z = cvtpk(v[4].x, v[5].x); pkA.w = cvtpk(v[6].x, v[7].x);
        pkB.x = cvtpk(v[0].y, v[1].y); pkB.y = cvtpk(v[2].y, v[3].y);
        pkB.z = cvtpk(v[4].y, v[5].y); pkB.w = cvtpk(v[6].y, v[7].y);
        *(uint4*)&xl[buf][(size_t)(2 * lane)     * 40 + w * 8] = pkA;
        *(uint4*)&xl[buf][(size_t)(2 * lane + 1) * 40 + w * 8] = pkB;
    };

    f32x4 acc[8][2];
    const f32x4 zz = {0.f, 0.f, 0.f, 0.f};
#pragma unroll
    for (int m = 0; m < 8; ++m) { acc[m][0] = zz; acc[m][1] = zz; }

    loads(0); packw(0);
    __syncthreads();

    for (int s = 0; s < 16; ++s) {
        if (s < 15) loads(s + 1);           // in flight across the MFMA cluster
        const u16* xbuf = xl[s & 1];
        s16x8 bf0 = *(const s16x8*)&xbuf[(w * 32 +      p16) * 40 + lg * 8];
        s16x8 bf1 = *(const s16x8*)&xbuf[(w * 32 + 16 + p16) * 40 + lg * 8];
#pragma unroll
        for (int m = 0; m < 8; ++m) {
            s16x8 af = *(const s16x8*)(wdf + ((size_t)((s * 8 + m) * 64 + lane)) * 8);
            acc[m][0] = __builtin_amdgcn_mfma_f32_16x16x32_bf16(af, bf0, acc[m][0], 0, 0, 0);
            acc[m][1] = __builtin_amdgcn_mfma_f32_16x16x32_bf16(af, bf1, acc[m][1], 0, 0, 0);
        }
        if (s < 15) packw((s + 1) & 1);     // vmcnt wait lands here, post-MFMA
        __syncthreads();
    }

    // epilogue: bias, hd store (bf16 via cvt_pk), LN stats
#pragma unroll
    for (int n = 0; n < 2; ++n) {
        const int hwpx = px0 + w * 32 + n * 16 + p16;
        const bool ok = hwpx < HW;
        float sum = 0.f, sq = 0.f;
        const size_t hbase = ((size_t)(b * HW + (ok ? hwpx : 0)) * 8 + t) * 128 + lg * 4;
#pragma unroll
        for (int m = 0; m < 8; ++m) {
            float4 bv = *(const float4*)(bd + m * 16 + lg * 4);
            float v0 = acc[m][n].x + bv.x;
            float v1 = acc[m][n].y + bv.y;
            float v2 = acc[m][n].z + bv.z;
            float v3 = acc[m][n].w + bv.w;
            sum += v0 + v1 + v2 + v3;
            sq  += v0*v0 + v1*v1 + v2*v2 + v3*v3;
            if (ok) {
                uint2 o;
                o.x = cvtpk(v0, v1);
                o.y = cvtpk(v2, v3);
                *(uint2*)(hd + hbase + m * 16) = o;
            }
        }
        // reduce the 4 lane-groups holding this pixel's 128 channels
        sum += __shfl_xor(sum, 16); sum += __shfl_xor(sum, 32);
        sq  += __shfl_xor(sq, 16);  sq  += __shfl_xor(sq, 32);
        if (ok && lg == 0) {
            float mu  = sum * (1.f / 128.f);
            float var = sq  * (1.f / 128.f) - mu * mu;
            float2 s2 = make_float2(mu, rsqrtf(var + 1e-5f));
            *(float2*)(st + ((size_t)(b * HW + hwpx) * 8 + t) * 2) = s2;
        }
    }
}

// ---------------------------------------------------------------------------
// k2a: motion shift + 8x8 self-attention + residual. One wave per pixel,
// 4 px/block. XCD-chunked mapping: XCD x owns batch b = x, so the (h+1)-row
// hd re-read hits the same XCD's L2 (unchanged from R9).
// ---------------------------------------------------------------------------
__global__ __launch_bounds__(256) void k2a_attn(
    const u16* __restrict__ hd, const float* __restrict__ st,
    u16* __restrict__ h2f)
{
    __shared__ float ql[4][8 * 132];
    __shared__ float pl[4][8][9];

    const int tid = threadIdx.x, wid = tid >> 6, lane = tid & 63;
    const int h = blockIdx.x;                        // 0..6271
    const int P = ((h & 7) * 784 + (h >> 3)) * 4 + wid;
    const int b = P / HW;
    const int hw = P - b * HW;
    const int hrow = hw / WROW;
    const bool hasnext = hrow < (WROW - 1);

    const u16* cur = hd + (size_t)P * 1024;
    const int tq = lane >> 3, cbase = (lane & 7) * 16;   // this lane: t=tq, c=cbase..+15

    uint4 c0 = *(const uint4*)(cur + tq * 128 + cbase);
    uint4 c1 = *(const uint4*)(cur + tq * 128 + cbase + 8);
    float2 ms = *(const float2*)(st + ((size_t)P * 8 + tq) * 2);

    float hv[16];
    hv[0]=bf2f(c0.x&0xffff); hv[1]=bf2f(c0.x>>16); hv[2]=bf2f(c0.y&0xffff); hv[3]=bf2f(c0.y>>16);
    hv[4]=bf2f(c0.z&0xffff); hv[5]=bf2f(c0.z>>16); hv[6]=bf2f(c0.w&0xffff); hv[7]=bf2f(c0.w>>16);
    hv[8]=bf2f(c1.x&0xffff); hv[9]=bf2f(c1.x>>16); hv[10]=bf2f(c1.y&0xffff); hv[11]=bf2f(c1.y>>16);
    hv[12]=bf2f(c1.z&0xffff); hv[13]=bf2f(c1.z>>16); hv[14]=bf2f(c1.w&0xffff); hv[15]=bf2f(c1.w>>16);

    float qv[16];
    if (hasnext) {
        const u16* nx = cur + (size_t)WROW * 1024;
        uint4 n0 = *(const uint4*)(nx + tq * 128 + cbase);
        uint4 n1 = *(const uint4*)(nx + tq * 128 + cbase + 8);
        float2 mn = *(const float2*)(st + ((size_t)(P + WROW) * 8 + tq) * 2);
        float nv[16];
        nv[0]=bf2f(n0.x&0xffff); nv[1]=bf2f(n0.x>>16); nv[2]=bf2f(n0.y&0xffff); nv[3]=bf2f(n0.y>>16);
        nv[4]=bf2f(n0.z&0xffff); nv[5]=bf2f(n0.z>>16); nv[6]=bf2f(n0.w&0xffff); nv[7]=bf2f(n0.w>>16);
        nv[8]=bf2f(n1.x&0xffff); nv[9]=bf2f(n1.x>>16); nv[10]=bf2f(n1.y&0xffff); nv[11]=bf2f(n1.y>>16);
        nv[12]=bf2f(n1.z&0xffff); nv[13]=bf2f(n1.z>>16); nv[14]=bf2f(n1.w&0xffff); nv[15]=bf2f(n1.w>>16);
#pragma unroll
        for (int i = 0; i < 16; ++i)
            qv[i] = (nv[i] - mn.x) * mn.y - (hv[i] - ms.x) * ms.y;
    } else {
#pragma unroll
        for (int i = 0; i < 16; ++i)
            qv[i] = -(hv[i] - ms.x) * ms.y;
    }

    float* qrow = &ql[wid][tq * 132 + cbase];
#pragma unroll
    for (int i = 0; i < 4; ++i)
        *(float4*)(qrow + i * 4) = make_float4(qv[4*i], qv[4*i+1], qv[4*i+2], qv[4*i+3]);
    __syncthreads();

    // S[t][s] = q[t].q[s]/sqrt(128); lane = t*8+s
    const int tt = lane >> 3, ss = lane & 7;
    const float* qt = &ql[wid][tt * 132];
    const float* qs = &ql[wid][ss * 132];
    float dot = 0.f;
#pragma unroll 8
    for (int c4 = 0; c4 < 32; ++c4) {
        float4 a4 = *(const float4*)(qt + c4 * 4);
        float4 g4 = *(const float4*)(qs + c4 * 4);
        dot += a4.x*g4.x + a4.y*g4.y + a4.z*g4.z + a4.w*g4.w;
    }
    dot *= 0.08838834764831845f;   // 1/sqrt(128)
    float mx = dot;
    mx = fmaxf(mx, __shfl_xor(mx, 1));
    mx = fmaxf(mx, __shfl_xor(mx, 2));
    mx = fmaxf(mx, __shfl_xor(mx, 4));
    float e = __expf(dot - mx);
    float sm = e;
    sm += __shfl_xor(sm, 1); sm += __shfl_xor(sm, 2); sm += __shfl_xor(sm, 4);
    pl[wid][tt][ss] = e / sm;
    __syncthreads();

    // attn = P @ q + residual(hd)
    float at[16];
#pragma unroll
    for (int i = 0; i < 16; ++i) at[i] = hv[i];
#pragma unroll
    for (int s = 0; s < 8; ++s) {
        float p = pl[wid][tq][s];
        const float* qsr = &ql[wid][s * 132 + cbase];
#pragma unroll
        for (int i4 = 0; i4 < 4; ++i4) {
            float4 q4 = *(const float4*)(qsr + i4 * 4);
            at[4*i4+0] += p * q4.x; at[4*i4+1] += p * q4.y;
            at[4*i4+2] += p * q4.z; at[4*i4+3] += p * q4.w;
        }
    }

    // store in k2b fragment layout
    const int hwq = hw >> 4, pp = hw & 15;
    const size_t base = ((((size_t)(b * 8 + tq) * HWQ + hwq) * 16 + (cbase >> 3)) * 16 + pp) * 8;
    uint4 o0, o1;
    o0.x = pk2(at[0], at[1]);  o0.y = pk2(at[2], at[3]);
    o0.z = pk2(at[4], at[5]);  o0.w = pk2(at[6], at[7]);
    o1.x = pk2(at[8], at[9]);  o1.y = pk2(at[10], at[11]);
    o1.z = pk2(at[12], at[13]); o1.w = pk2(at[14], at[15]);
    *(uint4*)(h2f + base) = o0;
    *(uint4*)(h2f + base + 128) = o1;   // rq+1 (stride 16px*8e)
}

// ---------------------------------------------------------------------------
// k2b: conv_up (M=px, N=16 o, K=128) + sigmoid gate + residual.
// Nontemporal out stores + x loads (R11 winner, byte-identical). 4
// independent waves/block, no barriers, private LDS slabs, XCD-chunked.
// ---------------------------------------------------------------------------
__global__ __launch_bounds__(256, 8) void k2b_up_out(
    const u16* __restrict__ h2f, const u16* __restrict__ wuf,
    const float* __restrict__ bu, const float* __restrict__ x,
    float* __restrict__ out)
{
    __shared__ float sl[4][16 * 68];       // per-wave private slabs, 17.4 KB

    const int tid = threadIdx.x, lane = tid & 63, w = tid >> 6;
    const int h = blockIdx.x;              // 0..2047
    const int slot = h >> 3;               // 0..255
    const int bt = (h & 7) * 8 + (slot >> 5);
    const int oc = slot & 31;              // o-chunk: o = oc*16 .. +15
    const int q  = w;                      // wave = px-quarter phase
    const int p16 = lane & 15, lg = lane >> 4;
    float* slw = sl[w];

    // B-frags: W_up rows o = oc*16 + p16, k = s*32 + lg*8 + j (live all kernel)
    s16x8 wf[4];
#pragma unroll
    for (int s = 0; s < 4; ++s)
        wf[s] = *(const s16x8*)(wuf + ((size_t)((oc * 4 + s) * 64 + lane)) * 8);

    // bias for this lane's 4 readback rows (row ol = i*4 + lg)
    float bvr[4];
#pragma unroll
    for (int i = 0; i < 4; ++i) bvr[i] = bu[oc * 16 + i * 4 + lg];

    const u16* bp0 = h2f + (size_t)bt * HWQ * 2048;
    const size_t xrow = (size_t)bt * CIN * HW + (size_t)(oc * 16) * HW;

    const int ng = (q == 0) ? 13 : 12;     // wave 0 of each (bt,oc) takes tail
    for (int it = 0; it < ng; ++it) {
        const int g = (it < 12) ? (it * 4 + q) : 48;   // 64-px group id
        const int px0 = g * 64;

        // 1. prefetch x for this group (nontemporal: zero reuse, don't allocate)
        f32x4 xv[4];
#pragma unroll
        for (int i = 0; i < 4; ++i)
            xv[i] = __builtin_nontemporal_load(
                (const f32x4*)(x + xrow + (size_t)(i * 4 + lg) * HW + px0 + p16 * 4));

        // 2. four 16-px MFMA tiles -> LDS slab [o=p16][px_local]
#pragma unroll
        for (int tt = 0; tt < 4; ++tt) {
            const u16* bp = bp0 + (size_t)(g * 4 + tt) * 2048;
            f32x4 a = {0.f, 0.f, 0.f, 0.f};
#pragma unroll
            for (int s = 0; s < 4; ++s) {
                s16x8 af = *(const s16x8*)(bp + ((size_t)((s * 4 + lg) * 16 + p16)) * 8);
                a = __builtin_amdgcn_mfma_f32_16x16x32_bf16(af, wf[s], a, 0, 0, 0);
            }
            // D: col=p16 -> o_local, row=lg*4+r -> px within tile
            *(f32x4*)&slw[p16 * 68 + tt * 16 + lg * 4] = a;
        }
        // intra-wave LDS dependency: compiler inserts lgkmcnt, no barrier.

        // 3. readback px-major + gate + nontemporal store
#pragma unroll
        for (int i = 0; i < 4; ++i) {
            const int ol = i * 4 + lg;
            f32x4 a4 = *(const f32x4*)&slw[ol * 68 + p16 * 4];
            const size_t off = xrow + (size_t)ol * HW + px0 + p16 * 4;
            f32x4 rr;
            rr.x = xv[i].x * (1.f + 1.f / (1.f + __expf(-(a4.x + bvr[i]))));
            rr.y = xv[i].y * (1.f + 1.f / (1.f + __expf(-(a4.y + bvr[i]))));
            rr.z = xv[i].z * (1.f + 1.f / (1.f + __expf(-(a4.z + bvr[i]))));
            rr.w = xv[i].w * (1.f + 1.f / (1.f + __expf(-(a4.w + bvr[i]))));
            __builtin_nontemporal_store(rr, (f32x4*)(out + off));
        }
    }
}

// ---------------------------------------------------------------------------
extern "C" void kernel_launch(void* const* d_in, const int* in_sizes, int n_in,
                              void* d_out, int out_size, void* d_ws, size_t ws_size,
                              hipStream_t stream)
{
    (void)in_sizes; (void)n_in; (void)out_size; (void)ws_size;
    const float* x  = (const float*)d_in[0];
    const float* Wd = (const float*)d_in[1];
    const float* bd = (const float*)d_in[2];
    const float* Wu = (const float*)d_in[3];
    const float* bu = (const float*)d_in[4];
    float* out = (float*)d_out;

    // workspace (bytes, all 256-aligned):
    //   hd  : 25,690,112 bf16 = 51,380,224   (conv_down out, (b,hw,t,c))
    //   h2f : 25,690,112 bf16 = 51,380,224   (attn out, k2b frag layout)
    //   st  :    401,408 f32  =  1,605,632   (LN mu/rstd per (pixel,t))
    //   wdf :     65,536 bf16 =    131,072   (W_down frag-packed)
    //   wuf :     65,536 bf16 =    131,072   (W_up   frag-packed)
    char* wsp = (char*)d_ws;
    u16*  hd  = (u16*)wsp;                 wsp += 51380224;
    u16*  h2f = (u16*)wsp;                 wsp += 51380224;
    float* st = (float*)wsp;               wsp += 1605632;
    u16*  wdf = (u16*)wsp;                 wsp += 131072;
    u16*  wuf = (u16*)wsp;                 wsp += 131072;

    kprep     <<<dim3(64),   256, 0, stream>>>(Wd, Wu, wdf, wuf);
    k1_down_ln<<<dim3(1600), 256, 0, stream>>>(x, wdf, bd, hd, st);
    k2a_attn  <<<dim3(6272), 256, 0, stream>>>(hd, st, h2f);
    k2b_up_out<<<dim3(2048), 256, 0, stream>>>(h2f, wuf, bu, x, out);
}

// Round 14
// 375.862 us; speedup vs baseline: 1.0550x; 1.0081x over previous
//
#include <hip/hip_runtime.h>
#include <cstdint>
#include <cstddef>

// Problem constants: B=8, T=8, C=512, R=128, H=W=56, HW=3136, BT=64
#define HW   3136
#define WROW 56
#define CIN  512
#define RMID 128
#define HWQ  196   // HW/16

typedef unsigned int  u32;
typedef unsigned short u16;
typedef __attribute__((ext_vector_type(8))) short s16x8;   // 8 bf16 = 4 VGPR
typedef __attribute__((ext_vector_type(4))) float f32x4;   // MFMA acc / nt IO

__device__ __forceinline__ float bf2f(u32 bits16) {
    return __uint_as_float(bits16 << 16);
}
// HW packed conversion: dst = {lo: bf16(a), hi: bf16(b)} — single VALU instr,
// RNE. No builtin on gfx950 -> inline asm.
__device__ __forceinline__ u32 cvtpk(float a, float b) {
    u32 r;
    asm("v_cvt_pk_bf16_f32 %0, %1, %2" : "=v"(r) : "v"(a), "v"(b));
    return r;
}

// ---------------------------------------------------------------------------
// Prep: pack W_down (128x512) and W_up (512x128) into MFMA fragment order.
// Frag k-mapping (shared by ALL MFMA users in this file): k = lg*8 + j,
// lg = lane>>4. Fragment for (k-step s, tile): lane l holds
// W[tile*16 + (l&15)][s*32 + lg*8 + j], stored at ((g*64)+l)*8+j so a frag
// load is one contiguous-1KB-per-wave b128 read. The same bytes serve as an
// A-frag (rows = l&15) or a B-frag (cols = l&15) depending on operand slot.
// ---------------------------------------------------------------------------
__global__ __launch_bounds__(256) void kprep(
    const float* __restrict__ Wd, const float* __restrict__ Wu,
    u16* __restrict__ wdf, u16* __restrict__ wuf)
{
    const int t = blockIdx.x * 256 + threadIdx.x;   // 0..16383
    const int l = t & 63, g = t >> 6;               // g 0..255
    const int lo = l & 15, hi = l >> 4;
    const float* src;
    u16* dst;
    if (g < 128) {                                  // W_down: s(16) x m(8)
        const int s = g >> 3, m = g & 7;
        src = Wd + (size_t)(m * 16 + lo) * CIN + s * 32 + hi * 8;
        dst = wdf + (size_t)t * 8;                  // (g*64+l)*8
    } else {                                        // W_up: mt(32) x s(4)
        const int g2 = g - 128;
        const int mt = g2 >> 2, s = g2 & 3;
        src = Wu + (size_t)(mt * 16 + lo) * RMID + s * 32 + hi * 8;
        dst = wuf + (size_t)(t - 8192) * 8;
    }
    float4 a = *(const float4*)src;
    float4 b = *(const float4*)(src + 4);
    uint4 o;
    o.x = cvtpk(a.x, a.y); o.y = cvtpk(a.z, a.w);
    o.z = cvtpk(b.x, b.y); o.w = cvtpk(b.z, b.w);
    *(uint4*)dst = o;
}

// ---------------------------------------------------------------------------
// k1: conv_down (M=128, K=512, N=px) via bf16 MFMA + LayerNorm stats.
// R13 winner: 1-deep prefetch, 2-buffer LDS, one barrier/step,
// v_cvt_pk_bf16_f32 for all f32->bf16 packing. (byte-identical to R13)
// ---------------------------------------------------------------------------
__global__ __launch_bounds__(256) void k1_down_ln(
    const float* __restrict__ x, const u16* __restrict__ wdf,
    const float* __restrict__ bd, u16* __restrict__ hd,
    float* __restrict__ st)
{
    __shared__ u16 xl[2][128 * 40];    // 20.4 KB double-buffered

    const int tid  = threadIdx.x;
    const int lane = tid & 63, w = tid >> 6;
    // bijective XCD-chunked remap: grid 1600 = 8 xcd * 8 bt * 25 chunks
    const int h = blockIdx.x;
    const int slot = h >> 3;                    // 0..199
    const int bt = (h & 7) * 8 + slot / 25;
    const int px0 = (slot % 25) * 128;
    const int b = bt >> 3, t = bt & 7;

    // staging role: wave w = c-oct w; lane = px-pair (2 px per thread)
    const int pxp2 = px0 + 2 * lane;
    const int pxa = (pxp2 > HW - 2) ? (HW - 2) : pxp2;   // clamp tail (dup reads)
    const float* xb = x + (size_t)bt * CIN * HW + pxa;

    // compute role
    const int p16 = lane & 15, lg = lane >> 4;

    float2 v[8];
    auto loads = [&](int s) {
        const float* xs = xb + (size_t)(s * 32 + w * 8) * HW;
#pragma unroll
        for (int j = 0; j < 8; ++j)
            v[j] = *(const float2*)(xs + (size_t)j * HW);
    };
    auto packw = [&](int buf) {
        uint4 pkA, pkB;
        pkA.x = cvtpk(v[0].x, v[1].x); pkA.y = cvtpk(v[2].x, v[3].x);
        pkA.z = cvtpk(v[4].x, v[5].x); pkA.w = cvtpk(v[6].x, v[7].x);
        pkB.x = cvtpk(v[0].y, v[1].y); pkB.y = cvtpk(v[2].y, v[3].y);
        pkB.z = cvtpk(v[4].y, v[5].y); pkB.w = cvtpk(v[6].y, v[7].y);
        *(uint4*)&xl[buf][(size_t)(2 * lane)     * 40 + w * 8] = pkA;
        *(uint4*)&xl[buf][(size_t)(2 * lane + 1) * 40 + w * 8] = pkB;
    };

    f32x4 acc[8][2];
    const f32x4 zz = {0.f, 0.f, 0.f, 0.f};
#pragma unroll
    for (int m = 0; m < 8; ++m) { acc[m][0] = zz; acc[m][1] = zz; }

    loads(0); packw(0);
    __syncthreads();

    for (int s = 0; s < 16; ++s) {
        if (s < 15) loads(s + 1);           // in flight across the MFMA cluster
        const u16* xbuf = xl[s & 1];
        s16x8 bf0 = *(const s16x8*)&xbuf[(w * 32 +      p16) * 40 + lg * 8];
        s16x8 bf1 = *(const s16x8*)&xbuf[(w * 32 + 16 + p16) * 40 + lg * 8];
#pragma unroll
        for (int m = 0; m < 8; ++m) {
            s16x8 af = *(const s16x8*)(wdf + ((size_t)((s * 8 + m) * 64 + lane)) * 8);
            acc[m][0] = __builtin_amdgcn_mfma_f32_16x16x32_bf16(af, bf0, acc[m][0], 0, 0, 0);
            acc[m][1] = __builtin_amdgcn_mfma_f32_16x16x32_bf16(af, bf1, acc[m][1], 0, 0, 0);
        }
        if (s < 15) packw((s + 1) & 1);     // vmcnt wait lands here, post-MFMA
        __syncthreads();
    }

    // epilogue: bias, hd store (bf16 via cvt_pk), LN stats
#pragma unroll
    for (int n = 0; n < 2; ++n) {
        const int hwpx = px0 + w * 32 + n * 16 + p16;
        const bool ok = hwpx < HW;
        float sum = 0.f, sq = 0.f;
        const size_t hbase = ((size_t)(b * HW + (ok ? hwpx : 0)) * 8 + t) * 128 + lg * 4;
#pragma unroll
        for (int m = 0; m < 8; ++m) {
            float4 bv = *(const float4*)(bd + m * 16 + lg * 4);
            float v0 = acc[m][n].x + bv.x;
            float v1 = acc[m][n].y + bv.y;
            float v2 = acc[m][n].z + bv.z;
            float v3 = acc[m][n].w + bv.w;
            sum += v0 + v1 + v2 + v3;
            sq  += v0*v0 + v1*v1 + v2*v2 + v3*v3;
            if (ok) {
                uint2 o;
                o.x = cvtpk(v0, v1);
                o.y = cvtpk(v2, v3);
                *(uint2*)(hd + hbase + m * 16) = o;
            }
        }
        // reduce the 4 lane-groups holding this pixel's 128 channels
        sum += __shfl_xor(sum, 16); sum += __shfl_xor(sum, 32);
        sq  += __shfl_xor(sq, 16);  sq  += __shfl_xor(sq, 32);
        if (ok && lg == 0) {
            float mu  = sum * (1.f / 128.f);
            float var = sq  * (1.f / 128.f) - mu * mu;
            float2 s2 = make_float2(mu, rsqrtf(var + 1e-5f));
            *(float2*)(st + ((size_t)(b * HW + hwpx) * 8 + t) * 2) = s2;
        }
    }
}

// ---------------------------------------------------------------------------
// k2a: motion shift + 8x8 self-attention + residual. One wave per pixel,
// 4 px/block, XCD-chunked (XCD x owns batch x). Round 14: output pack via
// v_cvt_pk_bf16_f32 (16 instrs instead of ~112 VALU bit-twiddle ops).
// ---------------------------------------------------------------------------
__global__ __launch_bounds__(256) void k2a_attn(
    const u16* __restrict__ hd, const float* __restrict__ st,
    u16* __restrict__ h2f)
{
    __shared__ float ql[4][8 * 132];
    __shared__ float pl[4][8][9];

    const int tid = threadIdx.x, wid = tid >> 6, lane = tid & 63;
    const int h = blockIdx.x;                        // 0..6271
    const int P = ((h & 7) * 784 + (h >> 3)) * 4 + wid;
    const int b = P / HW;
    const int hw = P - b * HW;
    const int hrow = hw / WROW;
    const bool hasnext = hrow < (WROW - 1);

    const u16* cur = hd + (size_t)P * 1024;
    const int tq = lane >> 3, cbase = (lane & 7) * 16;   // this lane: t=tq, c=cbase..+15

    uint4 c0 = *(const uint4*)(cur + tq * 128 + cbase);
    uint4 c1 = *(const uint4*)(cur + tq * 128 + cbase + 8);
    float2 ms = *(const float2*)(st + ((size_t)P * 8 + tq) * 2);

    float hv[16];
    hv[0]=bf2f(c0.x&0xffff); hv[1]=bf2f(c0.x>>16); hv[2]=bf2f(c0.y&0xffff); hv[3]=bf2f(c0.y>>16);
    hv[4]=bf2f(c0.z&0xffff); hv[5]=bf2f(c0.z>>16); hv[6]=bf2f(c0.w&0xffff); hv[7]=bf2f(c0.w>>16);
    hv[8]=bf2f(c1.x&0xffff); hv[9]=bf2f(c1.x>>16); hv[10]=bf2f(c1.y&0xffff); hv[11]=bf2f(c1.y>>16);
    hv[12]=bf2f(c1.z&0xffff); hv[13]=bf2f(c1.z>>16); hv[14]=bf2f(c1.w&0xffff); hv[15]=bf2f(c1.w>>16);

    float qv[16];
    if (hasnext) {
        const u16* nx = cur + (size_t)WROW * 1024;
        uint4 n0 = *(const uint4*)(nx + tq * 128 + cbase);
        uint4 n1 = *(const uint4*)(nx + tq * 128 + cbase + 8);
        float2 mn = *(const float2*)(st + ((size_t)(P + WROW) * 8 + tq) * 2);
        float nv[16];
        nv[0]=bf2f(n0.x&0xffff); nv[1]=bf2f(n0.x>>16); nv[2]=bf2f(n0.y&0xffff); nv[3]=bf2f(n0.y>>16);
        nv[4]=bf2f(n0.z&0xffff); nv[5]=bf2f(n0.z>>16); nv[6]=bf2f(n0.w&0xffff); nv[7]=bf2f(n0.w>>16);
        nv[8]=bf2f(n1.x&0xffff); nv[9]=bf2f(n1.x>>16); nv[10]=bf2f(n1.y&0xffff); nv[11]=bf2f(n1.y>>16);
        nv[12]=bf2f(n1.z&0xffff); nv[13]=bf2f(n1.z>>16); nv[14]=bf2f(n1.w&0xffff); nv[15]=bf2f(n1.w>>16);
#pragma unroll
        for (int i = 0; i < 16; ++i)
            qv[i] = (nv[i] - mn.x) * mn.y - (hv[i] - ms.x) * ms.y;
    } else {
#pragma unroll
        for (int i = 0; i < 16; ++i)
            qv[i] = -(hv[i] - ms.x) * ms.y;
    }

    float* qrow = &ql[wid][tq * 132 + cbase];
#pragma unroll
    for (int i = 0; i < 4; ++i)
        *(float4*)(qrow + i * 4) = make_float4(qv[4*i], qv[4*i+1], qv[4*i+2], qv[4*i+3]);
    __syncthreads();

    // S[t][s] = q[t].q[s]/sqrt(128); lane = t*8+s
    const int tt = lane >> 3, ss = lane & 7;
    const float* qt = &ql[wid][tt * 132];
    const float* qs = &ql[wid][ss * 132];
    float dot = 0.f;
#pragma unroll 8
    for (int c4 = 0; c4 < 32; ++c4) {
        float4 a4 = *(const float4*)(qt + c4 * 4);
        float4 g4 = *(const float4*)(qs + c4 * 4);
        dot += a4.x*g4.x + a4.y*g4.y + a4.z*g4.z + a4.w*g4.w;
    }
    dot *= 0.08838834764831845f;   // 1/sqrt(128)
    float mx = dot;
    mx = fmaxf(mx, __shfl_xor(mx, 1));
    mx = fmaxf(mx, __shfl_xor(mx, 2));
    mx = fmaxf(mx, __shfl_xor(mx, 4));
    float e = __expf(dot - mx);
    float sm = e;
    sm += __shfl_xor(sm, 1); sm += __shfl_xor(sm, 2); sm += __shfl_xor(sm, 4);
    pl[wid][tt][ss] = e / sm;
    __syncthreads();

    // attn = P @ q + residual(hd)
    float at[16];
#pragma unroll
    for (int i = 0; i < 16; ++i) at[i] = hv[i];
#pragma unroll
    for (int s = 0; s < 8; ++s) {
        float p = pl[wid][tq][s];
        const float* qsr = &ql[wid][s * 132 + cbase];
#pragma unroll
        for (int i4 = 0; i4 < 4; ++i4) {
            float4 q4 = *(const float4*)(qsr + i4 * 4);
            at[4*i4+0] += p * q4.x; at[4*i4+1] += p * q4.y;
            at[4*i4+2] += p * q4.z; at[4*i4+3] += p * q4.w;
        }
    }

    // store in k2b fragment layout (cvt_pk: 16 instrs)
    const int hwq = hw >> 4, pp = hw & 15;
    const size_t base = ((((size_t)(b * 8 + tq) * HWQ + hwq) * 16 + (cbase >> 3)) * 16 + pp) * 8;
    uint4 o0, o1;
    o0.x = cvtpk(at[0], at[1]);   o0.y = cvtpk(at[2], at[3]);
    o0.z = cvtpk(at[4], at[5]);   o0.w = cvtpk(at[6], at[7]);
    o1.x = cvtpk(at[8], at[9]);   o1.y = cvtpk(at[10], at[11]);
    o1.z = cvtpk(at[12], at[13]); o1.w = cvtpk(at[14], at[15]);
    *(uint4*)(h2f + base) = o0;
    *(uint4*)(h2f + base + 128) = o1;   // rq+1 (stride 16px*8e)
}

// ---------------------------------------------------------------------------
// k2b: conv_up (M=px, N=16 o, K=128) + sigmoid gate + residual.
// Nontemporal out stores + x loads (R11 winner, byte-identical). 4
// independent waves/block, no barriers, private LDS slabs, XCD-chunked.
// ---------------------------------------------------------------------------
__global__ __launch_bounds__(256, 8) void k2b_up_out(
    const u16* __restrict__ h2f, const u16* __restrict__ wuf,
    const float* __restrict__ bu, const float* __restrict__ x,
    float* __restrict__ out)
{
    __shared__ float sl[4][16 * 68];       // per-wave private slabs, 17.4 KB

    const int tid = threadIdx.x, lane = tid & 63, w = tid >> 6;
    const int h = blockIdx.x;              // 0..2047
    const int slot = h >> 3;               // 0..255
    const int bt = (h & 7) * 8 + (slot >> 5);
    const int oc = slot & 31;              // o-chunk: o = oc*16 .. +15
    const int q  = w;                      // wave = px-quarter phase
    const int p16 = lane & 15, lg = lane >> 4;
    float* slw = sl[w];

    // B-frags: W_up rows o = oc*16 + p16, k = s*32 + lg*8 + j (live all kernel)
    s16x8 wf[4];
#pragma unroll
    for (int s = 0; s < 4; ++s)
        wf[s] = *(const s16x8*)(wuf + ((size_t)((oc * 4 + s) * 64 + lane)) * 8);

    // bias for this lane's 4 readback rows (row ol = i*4 + lg)
    float bvr[4];
#pragma unroll
    for (int i = 0; i < 4; ++i) bvr[i] = bu[oc * 16 + i * 4 + lg];

    const u16* bp0 = h2f + (size_t)bt * HWQ * 2048;
    const size_t xrow = (size_t)bt * CIN * HW + (size_t)(oc * 16) * HW;

    const int ng = (q == 0) ? 13 : 12;     // wave 0 of each (bt,oc) takes tail
    for (int it = 0; it < ng; ++it) {
        const int g = (it < 12) ? (it * 4 + q) : 48;   // 64-px group id
        const int px0 = g * 64;

        // 1. prefetch x for this group (nontemporal: zero reuse, don't allocate)
        f32x4 xv[4];
#pragma unroll
        for (int i = 0; i < 4; ++i)
            xv[i] = __builtin_nontemporal_load(
                (const f32x4*)(x + xrow + (size_t)(i * 4 + lg) * HW + px0 + p16 * 4));

        // 2. four 16-px MFMA tiles -> LDS slab [o=p16][px_local]
#pragma unroll
        for (int tt = 0; tt < 4; ++tt) {
            const u16* bp = bp0 + (size_t)(g * 4 + tt) * 2048;
            f32x4 a = {0.f, 0.f, 0.f, 0.f};
#pragma unroll
            for (int s = 0; s < 4; ++s) {
                s16x8 af = *(const s16x8*)(bp + ((size_t)((s * 4 + lg) * 16 + p16)) * 8);
                a = __builtin_amdgcn_mfma_f32_16x16x32_bf16(af, wf[s], a, 0, 0, 0);
            }
            // D: col=p16 -> o_local, row=lg*4+r -> px within tile
            *(f32x4*)&slw[p16 * 68 + tt * 16 + lg * 4] = a;
        }
        // intra-wave LDS dependency: compiler inserts lgkmcnt, no barrier.

        // 3. readback px-major + gate + nontemporal store
#pragma unroll
        for (int i = 0; i < 4; ++i) {
            const int ol = i * 4 + lg;
            f32x4 a4 = *(const f32x4*)&slw[ol * 68 + p16 * 4];
            const size_t off = xrow + (size_t)ol * HW + px0 + p16 * 4;
            f32x4 rr;
            rr.x = xv[i].x * (1.f + 1.f / (1.f + __expf(-(a4.x + bvr[i]))));
            rr.y = xv[i].y * (1.f + 1.f / (1.f + __expf(-(a4.y + bvr[i]))));
            rr.z = xv[i].z * (1.f + 1.f / (1.f + __expf(-(a4.z + bvr[i]))));
            rr.w = xv[i].w * (1.f + 1.f / (1.f + __expf(-(a4.w + bvr[i]))));
            __builtin_nontemporal_store(rr, (f32x4*)(out + off));
        }
    }
}

// ---------------------------------------------------------------------------
extern "C" void kernel_launch(void* const* d_in, const int* in_sizes, int n_in,
                              void* d_out, int out_size, void* d_ws, size_t ws_size,
                              hipStream_t stream)
{
    (void)in_sizes; (void)n_in; (void)out_size; (void)ws_size;
    const float* x  = (const float*)d_in[0];
    const float* Wd = (const float*)d_in[1];
    const float* bd = (const float*)d_in[2];
    const float* Wu = (const float*)d_in[3];
    const float* bu = (const float*)d_in[4];
    float* out = (float*)d_out;

    // workspace (bytes, all 256-aligned):
    //   hd  : 25,690,112 bf16 = 51,380,224   (conv_down out, (b,hw,t,c))
    //   h2f : 25,690,112 bf16 = 51,380,224   (attn out, k2b frag layout)
    //   st  :    401,408 f32  =  1,605,632   (LN mu/rstd per (pixel,t))
    //   wdf :     65,536 bf16 =    131,072   (W_down frag-packed)
    //   wuf :     65,536 bf16 =    131,072   (W_up   frag-packed)
    char* wsp = (char*)d_ws;
    u16*  hd  = (u16*)wsp;                 wsp += 51380224;
    u16*  h2f = (u16*)wsp;                 wsp += 51380224;
    float* st = (float*)wsp;               wsp += 1605632;
    u16*  wdf = (u16*)wsp;                 wsp += 131072;
    u16*  wuf = (u16*)wsp;                 wsp += 131072;

    kprep     <<<dim3(64),   256, 0, stream>>>(Wd, Wu, wdf, wuf);
    k1_down_ln<<<dim3(1600), 256, 0, stream>>>(x, wdf, bd, hd, st);
    k2a_attn  <<<dim3(6272), 256, 0, stream>>>(hd, st, h2f);
    k2b_up_out<<<dim3(2048), 256, 0, stream>>>(h2f, wuf, bu, x, out);
}